// Round 7
// baseline (76.712 us; speedup 1.0000x reference)
//
#include <hip/hip_runtime.h>

// BayesPosLinear via MFMA, K-split for occupancy:
//   out[s,b,o] = sum_i input[s,b,i] * exp(w_mu[o,i] + (1e-6+softplus(w_std_eta[o,i]))*eps_w[b,o,i])
//                + (b_mu[o] + (1e-6+softplus(b_std_eta[o]))*eps_b[b,o])
//   + KL(w), KL(b) scalars.
// S=16, B=32, IN=1024, OUT=1024.
//
// R7: R6's mfma_f32_16x16x32_bf16 mapping (verified), restructured for TLP:
//  - 2048 blocks x 256 thr: block = one (b, 16-o tile); its 4 waves each do one
//    K-quarter (256) -> 8192 waves total = 8 waves/SIMD (was 2). LDS reduce (4KB).
//  - A-fragments (input as bf16, MFMA chunk order) precomputed ONCE into d_ws by a
//    ~1us prepass -> per k-step A-load is a single 16B L2-hit dwordx4, no cvt VALU.
//  - sp table (softplus(w_eta)+1e-6) + both KLs in prepass (as R4-R6).
//  - __launch_bounds__(256,8): <=64 VGPR so all 8 waves/SIMD are resident.
//  - Fallback to R6 single-kernel path if ws too small.

constexpr int S_ = 16, B_ = 32, IN_ = 1024, OUT_ = 1024;

typedef __bf16 bf16x8 __attribute__((ext_vector_type(8)));
typedef float  f32x4  __attribute__((ext_vector_type(4)));

__device__ __forceinline__ float softplus_f(float x) {
    float e = __expf(-fabsf(x));
    return fmaxf(x, 0.0f) + __logf(1.0f + e);
}

// ---------------- prepass 1: sp table (optional) + both KLs ----------------
template<bool WRITE_SP>
__global__ __launch_bounds__(256) void bpl_pre_kernel(
    const float* __restrict__ w_mu, const float* __restrict__ w_eta,
    const float* __restrict__ b_mu, const float* __restrict__ b_eta,
    float* __restrict__ sp_out,   // [OUT,IN] = softplus(w_eta)+1e-6 (if WRITE_SP)
    float* __restrict__ kl)       // kl[0]=kl_w, kl[1]=kl_b (pre-zeroed)
{
    __shared__ float red[4];
    const int tid  = threadIdx.x;
    const int wid  = tid >> 6;
    const int lane = tid & 63;

    const size_t base = (size_t)blockIdx.x * IN_ + tid * 4;
    const float4 mu = *reinterpret_cast<const float4*>(&w_mu[base]);
    const float4 et = *reinterpret_cast<const float4*>(&w_eta[base]);
    const float m[4] = {mu.x, mu.y, mu.z, mu.w};
    const float e[4] = {et.x, et.y, et.z, et.w};

    float sp[4];
    float local = 0.0f;
    #pragma unroll
    for (int j = 0; j < 4; ++j) {
        sp[j] = __logf(1.0f + __expf(e[j])) + 1e-6f;   // w_eta in [-4,-2] -> stable
        local += -__logf(sp[j]) + 0.5f * fmaf(sp[j], sp[j], m[j] * m[j]) - 0.5f;
    }
    if (WRITE_SP) {
        float4 spv = {sp[0], sp[1], sp[2], sp[3]};
        *reinterpret_cast<float4*>(&sp_out[base]) = spv;
    }

    #pragma unroll
    for (int off = 32; off > 0; off >>= 1) local += __shfl_xor(local, off, 64);
    if (lane == 0) red[wid] = local;
    __syncthreads();
    if (tid == 0) atomicAdd(&kl[0], red[0] + red[1] + red[2] + red[3]);

    if (blockIdx.x != 0) return;

    float lb = 0.0f;
    #pragma unroll
    for (int j = 0; j < 4; ++j) {
        const int idx = tid * 4 + j;
        const float sd = softplus_f(b_eta[idx]) + 1e-6f;
        const float mm = b_mu[idx];
        lb += -__logf(sd) + 0.5f * fmaf(sd, sd, mm * mm) - 0.5f;
    }
    #pragma unroll
    for (int off = 32; off > 0; off >>= 1) lb += __shfl_xor(lb, off, 64);
    __syncthreads();
    if (lane == 0) red[wid] = lb;
    __syncthreads();
    if (tid == 0) atomicAdd(&kl[1], red[0] + red[1] + red[2] + red[3]);
}

// ---------------- prepass 2: input -> bf16 A-frags in d_ws ----------------
// chunk c in [0,2048) per b: kt=c>>6, lane=c&63, s=c&15, kg=(c>>4)&3, k=kt*32+kg*8+j.
// dest: a_ws[b*16384 + c*8 + j]. 32 blocks (one per b) x 256 thr x 8 chunks.
__global__ __launch_bounds__(256) void bpl_stage_a_kernel(
    const float* __restrict__ input,   // [S,B,IN]
    __bf16* __restrict__ a_ws)         // [B][2048][8] bf16
{
    const int b   = blockIdx.x;
    const int tid = threadIdx.x;
    #pragma unroll
    for (int j = 0; j < 8; ++j) {
        const int c  = tid + j * 256;
        const int s  = c & 15;
        const int k0 = ((c >> 6) << 5) | (((c >> 4) & 3) << 3);   // kt*32 + kg*8
        const float* src = input + ((size_t)s * B_ + b) * IN_ + k0;
        const float4 x0 = *reinterpret_cast<const float4*>(src);
        const float4 x1 = *reinterpret_cast<const float4*>(src + 4);
        bf16x8 v;
        v[0] = (__bf16)x0.x; v[1] = (__bf16)x0.y; v[2] = (__bf16)x0.z; v[3] = (__bf16)x0.w;
        v[4] = (__bf16)x1.x; v[5] = (__bf16)x1.y; v[6] = (__bf16)x1.z; v[7] = (__bf16)x1.w;
        *reinterpret_cast<bf16x8*>(&a_ws[(size_t)b * 16384 + (size_t)c * 8]) = v;
    }
}

// ---------------- main MFMA kernel (K-split x4) ----------------
// grid: 2048 blocks (xcd=blk&7 -> 128-o slice; rest: b=&31, ot=>>5), 256 thr.
// wave wid = K-quarter kq; lane: on=lane&15 (o-col), kg0=lane>>4 (k-subslot).
__global__ __launch_bounds__(256, 8) void bpl_mfma2_kernel(
    const float* __restrict__ w_mu,    // [OUT,IN]
    const float* __restrict__ w_sp,    // sp table in ws
    const float* __restrict__ b_mu,    // [OUT]
    const float* __restrict__ b_eta,   // [OUT]
    const float* __restrict__ eps_w,   // [B,OUT,IN]
    const float* __restrict__ eps_b,   // [B,OUT]
    const __bf16* __restrict__ a_ws,   // [B][2048][8] A-frags
    float* __restrict__ out)           // [S,B,OUT]
{
    __shared__ __align__(16) float red[4 * 64 * 4];   // [kq][lane][rr], 4KB

    const int blk = blockIdx.x;
    const int xcd = blk & 7;
    const int r_  = blk >> 3;          // 0..255
    const int b   = r_ & 31;
    const int ot  = r_ >> 5;           // 0..7
    const int o_base = xcd * 128 + ot * 16;

    const int tid  = threadIdx.x;
    const int kq   = tid >> 6;         // 0..3: K-quarter
    const int lane = tid & 63;
    const int on   = lane & 15;
    const int kg0  = lane >> 4;        // 0..3
    const int o_row = o_base + on;

    const int kbase = kq * 256 + kg0 * 8;
    const float* __restrict__ mu_p = w_mu + (size_t)o_row * IN_ + kbase;
    const float* __restrict__ sp_p = w_sp + (size_t)o_row * IN_ + kbase;
    const float* __restrict__ ep_p = eps_w + ((size_t)b * OUT_ + o_row) * IN_ + kbase;
    const __bf16* __restrict__ a_p = a_ws + (size_t)b * 16384 + (size_t)kq * 4096 + lane * 8;

    f32x4 acc = {0.0f, 0.0f, 0.0f, 0.0f};

    #pragma unroll
    for (int t = 0; t < 8; ++t) {
        const int i_ = t * 32;
        const float4 m0 = *reinterpret_cast<const float4*>(mu_p + i_);
        const float4 m1 = *reinterpret_cast<const float4*>(mu_p + i_ + 4);
        const float4 s0 = *reinterpret_cast<const float4*>(sp_p + i_);
        const float4 s1 = *reinterpret_cast<const float4*>(sp_p + i_ + 4);
        const float4 e0 = *reinterpret_cast<const float4*>(ep_p + i_);
        const float4 e1 = *reinterpret_cast<const float4*>(ep_p + i_ + 4);
        const bf16x8 afrag = *reinterpret_cast<const bf16x8*>(a_p + t * 512);

        const float mm[8] = {m0.x, m0.y, m0.z, m0.w, m1.x, m1.y, m1.z, m1.w};
        const float ss[8] = {s0.x, s0.y, s0.z, s0.w, s1.x, s1.y, s1.z, s1.w};
        const float ee[8] = {e0.x, e0.y, e0.z, e0.w, e1.x, e1.y, e1.z, e1.w};

        bf16x8 bfrag;
        #pragma unroll
        for (int q = 0; q < 8; ++q)
            bfrag[q] = (__bf16)__expf(fmaf(ss[q], ee[q], mm[q]));

        acc = __builtin_amdgcn_mfma_f32_16x16x32_bf16(afrag, bfrag, acc, 0, 0, 0);
    }

    *reinterpret_cast<f32x4*>(&red[(kq * 64 + lane) * 4]) = acc;
    __syncthreads();

    // thread tid -> output (s = tid>>4, o = o_base + (tid&15)); sum 4 K-quarters.
    {
        const int s  = tid >> 4;       // 0..15
        const int ol = tid & 15;
        const int srcLane = ((s >> 2) << 4) | ol;
        const int rr = s & 3;
        float v = red[(0 * 64 + srcLane) * 4 + rr] + red[(1 * 64 + srcLane) * 4 + rr]
                + red[(2 * 64 + srcLane) * 4 + rr] + red[(3 * 64 + srcLane) * 4 + rr];
        const int oo = o_base + ol;
        const float bias = fmaf(softplus_f(b_eta[oo]) + 1e-6f,
                                eps_b[(size_t)b * OUT_ + oo], b_mu[oo]);
        out[((size_t)s * B_ + b) * OUT_ + oo] = v + bias;
    }
}

// ---------------- fallback (R6 verified path, no ws) ----------------
__global__ __launch_bounds__(256, 4) void bpl_mfma_fb_kernel(
    const float* __restrict__ input, const float* __restrict__ w_mu,
    const float* __restrict__ w_eta, const float* __restrict__ b_mu,
    const float* __restrict__ b_eta, const float* __restrict__ eps_w,
    const float* __restrict__ eps_b, float* __restrict__ out)
{
    __shared__ __align__(16) __bf16 alds[16384];

    const int blk = blockIdx.x;
    const int xcd = blk & 7;
    const int r_  = blk >> 3;
    const int b   = r_ & 31;
    const int oh  = r_ >> 5;
    const int o_base = (xcd * 2 + oh) * 64;

    const int tid  = threadIdx.x;
    const int wid  = tid >> 6;
    const int lane = tid & 63;

    #pragma unroll
    for (int j = 0; j < 8; ++j) {
        const int c   = tid + j * 256;
        const int s   = c & 15;
        const int kgg = ((c >> 6) << 2) | ((c >> 4) & 3);
        const float* src = input + ((size_t)s * B_ + b) * IN_ + kgg * 8;
        const float4 x0 = *reinterpret_cast<const float4*>(src);
        const float4 x1 = *reinterpret_cast<const float4*>(src + 4);
        bf16x8 v;
        v[0] = (__bf16)x0.x; v[1] = (__bf16)x0.y; v[2] = (__bf16)x0.z; v[3] = (__bf16)x0.w;
        v[4] = (__bf16)x1.x; v[5] = (__bf16)x1.y; v[6] = (__bf16)x1.z; v[7] = (__bf16)x1.w;
        *reinterpret_cast<bf16x8*>(&alds[c * 8]) = v;
    }
    __syncthreads();

    const int on    = lane & 15;
    const int kg0   = lane >> 4;
    const int o_row = o_base + wid * 16 + on;

    const float* __restrict__ mu_p = w_mu  + (size_t)o_row * IN_ + kg0 * 8;
    const float* __restrict__ et_p = w_eta + (size_t)o_row * IN_ + kg0 * 8;
    const float* __restrict__ ep_p = eps_w + ((size_t)b * OUT_ + o_row) * IN_ + kg0 * 8;
    const __bf16* __restrict__ a_p = alds + lane * 8;

    f32x4 acc = {0.0f, 0.0f, 0.0f, 0.0f};
    #pragma unroll
    for (int kt = 0; kt < 32; ++kt) {
        const int i_ = kt * 32;
        const float4 m0 = *reinterpret_cast<const float4*>(mu_p + i_);
        const float4 m1 = *reinterpret_cast<const float4*>(mu_p + i_ + 4);
        const float4 s0 = *reinterpret_cast<const float4*>(et_p + i_);
        const float4 s1 = *reinterpret_cast<const float4*>(et_p + i_ + 4);
        const float4 e0 = *reinterpret_cast<const float4*>(ep_p + i_);
        const float4 e1 = *reinterpret_cast<const float4*>(ep_p + i_ + 4);
        const float mm[8] = {m0.x, m0.y, m0.z, m0.w, m1.x, m1.y, m1.z, m1.w};
        const float ss[8] = {s0.x, s0.y, s0.z, s0.w, s1.x, s1.y, s1.z, s1.w};
        const float ee[8] = {e0.x, e0.y, e0.z, e0.w, e1.x, e1.y, e1.z, e1.w};
        bf16x8 bfrag;
        #pragma unroll
        for (int q = 0; q < 8; ++q) {
            const float sp_ = __logf(1.0f + __expf(ss[q])) + 1e-6f;
            bfrag[q] = (__bf16)__expf(fmaf(sp_, ee[q], mm[q]));
        }
        const bf16x8 afrag = *reinterpret_cast<const bf16x8*>(a_p + kt * 512);
        acc = __builtin_amdgcn_mfma_f32_16x16x32_bf16(afrag, bfrag, acc, 0, 0, 0);
    }

    const float bias = fmaf(softplus_f(b_eta[o_row]) + 1e-6f,
                            eps_b[(size_t)b * OUT_ + o_row], b_mu[o_row]);
    #pragma unroll
    for (int rr = 0; rr < 4; ++rr) {
        const int s = kg0 * 4 + rr;
        out[((size_t)s * B_ + b) * OUT_ + o_row] = acc[rr] + bias;
    }
}

extern "C" void kernel_launch(void* const* d_in, const int* in_sizes, int n_in,
                              void* d_out, int out_size, void* d_ws, size_t ws_size,
                              hipStream_t stream)
{
    const float* input = (const float*)d_in[0];
    const float* w_mu  = (const float*)d_in[1];
    const float* w_eta = (const float*)d_in[2];
    const float* b_mu  = (const float*)d_in[3];
    const float* b_eta = (const float*)d_in[4];
    const float* eps_w = (const float*)d_in[5];
    const float* eps_b = (const float*)d_in[6];

    float* out = (float*)d_out;
    float* kl  = out + (size_t)S_ * B_ * OUT_;   // offsets 524288, 524289

    hipMemsetAsync(kl, 0, 2 * sizeof(float), stream);

    const size_t SP_BYTES = (size_t)OUT_ * IN_ * sizeof(float);           // 4 MB
    const size_t A_BYTES  = (size_t)B_ * 16384 * sizeof(__bf16);          // 1 MB
    if (ws_size >= SP_BYTES + A_BYTES) {
        float*  sp   = (float*)d_ws;
        __bf16* a_ws = (__bf16*)((char*)d_ws + SP_BYTES);
        bpl_pre_kernel<true><<<1024, 256, 0, stream>>>(w_mu, w_eta, b_mu, b_eta, sp, kl);
        bpl_stage_a_kernel<<<32, 256, 0, stream>>>(input, a_ws);
        bpl_mfma2_kernel<<<2048, 256, 0, stream>>>(w_mu, sp, b_mu, b_eta,
                                                   eps_w, eps_b, a_ws, out);
    } else {
        bpl_pre_kernel<false><<<1024, 256, 0, stream>>>(w_mu, w_eta, b_mu, b_eta,
                                                        nullptr, kl);
        bpl_mfma_fb_kernel<<<512, 256, 0, stream>>>(input, w_mu, w_eta, b_mu, b_eta,
                                                    eps_w, eps_b, out);
    }
}

// Round 8
// 62.028 us; speedup vs baseline: 1.2367x; 1.2367x over previous
//
#include <hip/hip_runtime.h>

// BayesPosLinear, split-pass MFMA design:
//   out[s,b,o] = sum_i input[s,b,i] * exp(w_mu[o,i] + (1e-6+softplus(w_std_eta[o,i]))*eps_w[b,o,i])
//                + (b_mu[o] + (1e-6+softplus(b_std_eta[o]))*eps_b[b,o])
//   + KL(w), KL(b).
// S=16, B=32, IN=1024, OUT=1024.
//
// R8: the fused kernel (R5-R7) is stuck at ~70us: 7 loads/k-step cannot be pipelined
// under any VGPR/occupancy tradeoff. Split into kernels that each pipeline trivially:
//  K1 bpl_pre    : sp = softplus(w_eta)+1e-6 table (4MB ws) + per-block kl_w partials.
//  K0 bpl_stage_a: input -> bf16 A-fragments (1MB ws)  [R7, verified]
//  K2 bpl_wgen   : w_bf16[b,o,i] = bf16(exp(fma(sp,eps,mu))) -> 64MB ws. Pure streamer.
//  K3 bpl_gemm   : R7's K-split-4 MFMA kernel, now 2 loads/k-step (w-frag + a-frag).
//  K4 bpl_klfin  : 1 block: sum kl_w partials + compute kl_b; direct writes, no atomics.
// No hipMemsetAsync in the main path. Fallback to R6/R7 verified path if ws too small.

constexpr int S_ = 16, B_ = 32, IN_ = 1024, OUT_ = 1024;

typedef __bf16 bf16x8 __attribute__((ext_vector_type(8)));
typedef float  f32x4  __attribute__((ext_vector_type(4)));

__device__ __forceinline__ float softplus_f(float x) {
    float e = __expf(-fabsf(x));
    return fmaxf(x, 0.0f) + __logf(1.0f + e);
}

// ---------------- K1: sp table + kl_w per-block partials ----------------
__global__ __launch_bounds__(256) void bpl_pre(
    const float* __restrict__ w_mu, const float* __restrict__ w_eta,
    float* __restrict__ sp_out,     // [OUT,IN]
    float* __restrict__ klw_part)   // [1024]
{
    __shared__ float red[4];
    const int tid  = threadIdx.x;
    const int wid  = tid >> 6;
    const int lane = tid & 63;

    const size_t base = (size_t)blockIdx.x * IN_ + tid * 4;
    const float4 mu = *reinterpret_cast<const float4*>(&w_mu[base]);
    const float4 et = *reinterpret_cast<const float4*>(&w_eta[base]);
    const float m[4] = {mu.x, mu.y, mu.z, mu.w};
    const float e[4] = {et.x, et.y, et.z, et.w};

    float sp[4];
    float local = 0.0f;
    #pragma unroll
    for (int j = 0; j < 4; ++j) {
        sp[j] = __logf(1.0f + __expf(e[j])) + 1e-6f;   // w_eta in [-4,-2] -> stable
        local += -__logf(sp[j]) + 0.5f * fmaf(sp[j], sp[j], m[j] * m[j]) - 0.5f;
    }
    float4 spv = {sp[0], sp[1], sp[2], sp[3]};
    *reinterpret_cast<float4*>(&sp_out[base]) = spv;

    #pragma unroll
    for (int off = 32; off > 0; off >>= 1) local += __shfl_xor(local, off, 64);
    if (lane == 0) red[wid] = local;
    __syncthreads();
    if (tid == 0) klw_part[blockIdx.x] = red[0] + red[1] + red[2] + red[3];
}

// ---------------- K0: input -> bf16 A-frags (R7, verified) ----------------
__global__ __launch_bounds__(256) void bpl_stage_a(
    const float* __restrict__ input,   // [S,B,IN]
    __bf16* __restrict__ a_ws)         // [B][2048][8]
{
    const int b   = blockIdx.x;
    const int tid = threadIdx.x;
    #pragma unroll
    for (int j = 0; j < 8; ++j) {
        const int c  = tid + j * 256;
        const int s  = c & 15;
        const int k0 = ((c >> 6) << 5) | (((c >> 4) & 3) << 3);   // kt*32 + kg*8
        const float* src = input + ((size_t)s * B_ + b) * IN_ + k0;
        const float4 x0 = *reinterpret_cast<const float4*>(src);
        const float4 x1 = *reinterpret_cast<const float4*>(src + 4);
        bf16x8 v;
        v[0] = (__bf16)x0.x; v[1] = (__bf16)x0.y; v[2] = (__bf16)x0.z; v[3] = (__bf16)x0.w;
        v[4] = (__bf16)x1.x; v[5] = (__bf16)x1.y; v[6] = (__bf16)x1.z; v[7] = (__bf16)x1.w;
        *reinterpret_cast<bf16x8*>(&a_ws[(size_t)b * 16384 + (size_t)c * 8]) = v;
    }
}

// ---------------- K2: w_bf16 = exp(fma(sp,eps,mu)) streamer ----------------
// 2048 blocks (xcd=blk&7 -> 128-o slice; b=(blk>>3)&31; osub=blk>>8), 256 thr.
// Block covers 16 o-rows x 1024 i = 64KB eps read, 32KB w write.
__global__ __launch_bounds__(256, 4) void bpl_wgen(
    const float* __restrict__ w_mu,    // [OUT,IN]
    const float* __restrict__ sp_t,    // [OUT,IN]
    const float* __restrict__ eps_w,   // [B,OUT,IN]
    __bf16* __restrict__ w_ws)         // [B,OUT,IN] bf16
{
    const int blk  = blockIdx.x;
    const int xcd  = blk & 7;
    const int r_   = blk >> 3;         // 0..255
    const int b    = r_ & 31;
    const int osub = r_ >> 5;          // 0..7
    const int o_base = xcd * 128 + osub * 16;

    const int tid = threadIdx.x;

    #pragma unroll
    for (int it = 0; it < 8; ++it) {
        const int e  = it * 2048 + tid * 8;     // 0..16383
        const int ol = e >> 10;                 // 0..15
        const int i0 = e & 1023;
        const int o  = o_base + ol;

        const size_t toff = (size_t)o * IN_ + i0;
        const size_t eoff = ((size_t)b * OUT_ + o) * IN_ + i0;

        const float4 m0 = *reinterpret_cast<const float4*>(w_mu + toff);
        const float4 m1 = *reinterpret_cast<const float4*>(w_mu + toff + 4);
        const float4 s0 = *reinterpret_cast<const float4*>(sp_t + toff);
        const float4 s1 = *reinterpret_cast<const float4*>(sp_t + toff + 4);
        const float4 e0 = *reinterpret_cast<const float4*>(eps_w + eoff);
        const float4 e1 = *reinterpret_cast<const float4*>(eps_w + eoff + 4);

        const float mm[8] = {m0.x, m0.y, m0.z, m0.w, m1.x, m1.y, m1.z, m1.w};
        const float ss[8] = {s0.x, s0.y, s0.z, s0.w, s1.x, s1.y, s1.z, s1.w};
        const float ee[8] = {e0.x, e0.y, e0.z, e0.w, e1.x, e1.y, e1.z, e1.w};

        bf16x8 v;
        #pragma unroll
        for (int q = 0; q < 8; ++q)
            v[q] = (__bf16)__expf(fmaf(ss[q], ee[q], mm[q]));

        *reinterpret_cast<bf16x8*>(&w_ws[eoff]) = v;
    }
}

// ---------------- K3: K-split-4 MFMA GEMM (2 loads per k-step) ----------------
// 2048 blocks (xcd=blk&7; b=(blk>>3)&31; ot=blk>>8), 256 thr = 4 waves (K-quarters).
__global__ __launch_bounds__(256, 8) void bpl_gemm(
    const __bf16* __restrict__ w_ws,   // [B,OUT,IN] bf16
    const __bf16* __restrict__ a_ws,   // [B][2048][8]
    const float* __restrict__ b_mu,    // [OUT]
    const float* __restrict__ b_eta,   // [OUT]
    const float* __restrict__ eps_b,   // [B,OUT]
    float* __restrict__ out)           // [S,B,OUT]
{
    __shared__ __align__(16) float red[4 * 64 * 4];   // [kq][lane][rr], 4KB

    const int blk = blockIdx.x;
    const int xcd = blk & 7;
    const int r_  = blk >> 3;          // 0..255
    const int b   = r_ & 31;
    const int ot  = r_ >> 5;           // 0..7
    const int o_base = xcd * 128 + ot * 16;

    const int tid  = threadIdx.x;
    const int kq   = tid >> 6;         // 0..3: K-quarter
    const int lane = tid & 63;
    const int on   = lane & 15;
    const int kg0  = lane >> 4;        // 0..3
    const int o_row = o_base + on;

    const int kbase = kq * 256 + kg0 * 8;
    const __bf16* __restrict__ w_p = w_ws + ((size_t)b * OUT_ + o_row) * IN_ + kbase;
    const __bf16* __restrict__ a_p = a_ws + (size_t)b * 16384 + (size_t)kq * 4096 + lane * 8;

    f32x4 acc = {0.0f, 0.0f, 0.0f, 0.0f};

    #pragma unroll
    for (int t = 0; t < 8; ++t) {
        const bf16x8 wf = *reinterpret_cast<const bf16x8*>(w_p + t * 32);
        const bf16x8 af = *reinterpret_cast<const bf16x8*>(a_p + t * 512);
        acc = __builtin_amdgcn_mfma_f32_16x16x32_bf16(af, wf, acc, 0, 0, 0);
    }

    *reinterpret_cast<f32x4*>(&red[(kq * 64 + lane) * 4]) = acc;
    __syncthreads();

    // thread tid -> (s = tid>>4, o = o_base + (tid&15)); sum the 4 K-quarters.
    {
        const int s  = tid >> 4;
        const int ol = tid & 15;
        const int srcLane = ((s >> 2) << 4) | ol;
        const int rr = s & 3;
        float v = red[(0 * 64 + srcLane) * 4 + rr] + red[(1 * 64 + srcLane) * 4 + rr]
                + red[(2 * 64 + srcLane) * 4 + rr] + red[(3 * 64 + srcLane) * 4 + rr];
        const int oo = o_base + ol;
        const float bias = fmaf(softplus_f(b_eta[oo]) + 1e-6f,
                                eps_b[(size_t)b * OUT_ + oo], b_mu[oo]);
        out[((size_t)s * B_ + b) * OUT_ + oo] = v + bias;
    }
}

// ---------------- K4: finalize both KLs (1 block, no atomics) ----------------
__global__ __launch_bounds__(256) void bpl_klfin(
    const float* __restrict__ klw_part,   // [1024]
    const float* __restrict__ b_mu, const float* __restrict__ b_eta,
    float* __restrict__ kl)               // kl[0]=kl_w, kl[1]=kl_b
{
    __shared__ float red[8];
    const int tid  = threadIdx.x;
    const int wid  = tid >> 6;
    const int lane = tid & 63;

    float lw = klw_part[tid] + klw_part[tid + 256]
             + klw_part[tid + 512] + klw_part[tid + 768];

    float lb = 0.0f;
    #pragma unroll
    for (int h = 0; h < 4; ++h) {
        const int o = tid + h * 256;
        const float sd = softplus_f(b_eta[o]) + 1e-6f;
        const float mm = b_mu[o];
        lb += -__logf(sd) + 0.5f * fmaf(sd, sd, mm * mm) - 0.5f;
    }

    #pragma unroll
    for (int off = 32; off > 0; off >>= 1) {
        lw += __shfl_xor(lw, off, 64);
        lb += __shfl_xor(lb, off, 64);
    }
    if (lane == 0) { red[wid] = lw; red[4 + wid] = lb; }
    __syncthreads();
    if (tid == 0) {
        kl[0] = red[0] + red[1] + red[2] + red[3];
        kl[1] = red[4] + red[5] + red[6] + red[7];
    }
}

// ---------------- fallback (R6/R7 verified path, no ws) ----------------
__global__ __launch_bounds__(256) void bpl_pre_fb(
    const float* __restrict__ w_mu, const float* __restrict__ w_eta,
    const float* __restrict__ b_mu, const float* __restrict__ b_eta,
    float* __restrict__ kl)
{
    __shared__ float red[4];
    const int tid  = threadIdx.x;
    const int wid  = tid >> 6;
    const int lane = tid & 63;

    const size_t base = (size_t)blockIdx.x * IN_ + tid * 4;
    const float4 mu = *reinterpret_cast<const float4*>(&w_mu[base]);
    const float4 et = *reinterpret_cast<const float4*>(&w_eta[base]);
    const float m[4] = {mu.x, mu.y, mu.z, mu.w};
    const float e[4] = {et.x, et.y, et.z, et.w};

    float local = 0.0f;
    #pragma unroll
    for (int j = 0; j < 4; ++j) {
        const float sp = __logf(1.0f + __expf(e[j])) + 1e-6f;
        local += -__logf(sp) + 0.5f * fmaf(sp, sp, m[j] * m[j]) - 0.5f;
    }
    #pragma unroll
    for (int off = 32; off > 0; off >>= 1) local += __shfl_xor(local, off, 64);
    if (lane == 0) red[wid] = local;
    __syncthreads();
    if (tid == 0) atomicAdd(&kl[0], red[0] + red[1] + red[2] + red[3]);

    if (blockIdx.x != 0) return;
    float lb = 0.0f;
    #pragma unroll
    for (int j = 0; j < 4; ++j) {
        const int idx = tid * 4 + j;
        const float sd = softplus_f(b_eta[idx]) + 1e-6f;
        const float mm = b_mu[idx];
        lb += -__logf(sd) + 0.5f * fmaf(sd, sd, mm * mm) - 0.5f;
    }
    #pragma unroll
    for (int off = 32; off > 0; off >>= 1) lb += __shfl_xor(lb, off, 64);
    __syncthreads();
    if (lane == 0) red[wid] = lb;
    __syncthreads();
    if (tid == 0) atomicAdd(&kl[1], red[0] + red[1] + red[2] + red[3]);
}

__global__ __launch_bounds__(256, 4) void bpl_mfma_fb(
    const float* __restrict__ input, const float* __restrict__ w_mu,
    const float* __restrict__ w_eta, const float* __restrict__ b_mu,
    const float* __restrict__ b_eta, const float* __restrict__ eps_w,
    const float* __restrict__ eps_b, float* __restrict__ out)
{
    __shared__ __align__(16) __bf16 alds[16384];

    const int blk = blockIdx.x;
    const int xcd = blk & 7;
    const int r_  = blk >> 3;
    const int b   = r_ & 31;
    const int oh  = r_ >> 5;
    const int o_base = (xcd * 2 + oh) * 64;

    const int tid  = threadIdx.x;
    const int wid  = tid >> 6;
    const int lane = tid & 63;

    #pragma unroll
    for (int j = 0; j < 8; ++j) {
        const int c   = tid + j * 256;
        const int s   = c & 15;
        const int kgg = ((c >> 6) << 2) | ((c >> 4) & 3);
        const float* src = input + ((size_t)s * B_ + b) * IN_ + kgg * 8;
        const float4 x0 = *reinterpret_cast<const float4*>(src);
        const float4 x1 = *reinterpret_cast<const float4*>(src + 4);
        bf16x8 v;
        v[0] = (__bf16)x0.x; v[1] = (__bf16)x0.y; v[2] = (__bf16)x0.z; v[3] = (__bf16)x0.w;
        v[4] = (__bf16)x1.x; v[5] = (__bf16)x1.y; v[6] = (__bf16)x1.z; v[7] = (__bf16)x1.w;
        *reinterpret_cast<bf16x8*>(&alds[c * 8]) = v;
    }
    __syncthreads();

    const int on    = lane & 15;
    const int kg0   = lane >> 4;
    const int o_row = o_base + wid * 16 + on;

    const float* __restrict__ mu_p = w_mu  + (size_t)o_row * IN_ + kg0 * 8;
    const float* __restrict__ et_p = w_eta + (size_t)o_row * IN_ + kg0 * 8;
    const float* __restrict__ ep_p = eps_w + ((size_t)b * OUT_ + o_row) * IN_ + kg0 * 8;
    const __bf16* __restrict__ a_p = alds + lane * 8;

    f32x4 acc = {0.0f, 0.0f, 0.0f, 0.0f};
    #pragma unroll
    for (int kt = 0; kt < 32; ++kt) {
        const int i_ = kt * 32;
        const float4 m0 = *reinterpret_cast<const float4*>(mu_p + i_);
        const float4 m1 = *reinterpret_cast<const float4*>(mu_p + i_ + 4);
        const float4 s0 = *reinterpret_cast<const float4*>(et_p + i_);
        const float4 s1 = *reinterpret_cast<const float4*>(et_p + i_ + 4);
        const float4 e0 = *reinterpret_cast<const float4*>(ep_p + i_);
        const float4 e1 = *reinterpret_cast<const float4*>(ep_p + i_ + 4);
        const float mm[8] = {m0.x, m0.y, m0.z, m0.w, m1.x, m1.y, m1.z, m1.w};
        const float ss[8] = {s0.x, s0.y, s0.z, s0.w, s1.x, s1.y, s1.z, s1.w};
        const float ee[8] = {e0.x, e0.y, e0.z, e0.w, e1.x, e1.y, e1.z, e1.w};
        bf16x8 bfrag;
        #pragma unroll
        for (int q = 0; q < 8; ++q) {
            const float sp_ = __logf(1.0f + __expf(ss[q])) + 1e-6f;
            bfrag[q] = (__bf16)__expf(fmaf(sp_, ee[q], mm[q]));
        }
        const bf16x8 afrag = *reinterpret_cast<const bf16x8*>(a_p + kt * 512);
        acc = __builtin_amdgcn_mfma_f32_16x16x32_bf16(afrag, bfrag, acc, 0, 0, 0);
    }

    const float bias = fmaf(softplus_f(b_eta[o_row]) + 1e-6f,
                            eps_b[(size_t)b * OUT_ + o_row], b_mu[o_row]);
    #pragma unroll
    for (int rr = 0; rr < 4; ++rr) {
        const int s = kg0 * 4 + rr;
        out[((size_t)s * B_ + b) * OUT_ + o_row] = acc[rr] + bias;
    }
}

extern "C" void kernel_launch(void* const* d_in, const int* in_sizes, int n_in,
                              void* d_out, int out_size, void* d_ws, size_t ws_size,
                              hipStream_t stream)
{
    const float* input = (const float*)d_in[0];
    const float* w_mu  = (const float*)d_in[1];
    const float* w_eta = (const float*)d_in[2];
    const float* b_mu  = (const float*)d_in[3];
    const float* b_eta = (const float*)d_in[4];
    const float* eps_w = (const float*)d_in[5];
    const float* eps_b = (const float*)d_in[6];

    float* out = (float*)d_out;
    float* kl  = out + (size_t)S_ * B_ * OUT_;   // offsets 524288, 524289

    // ws layout
    const size_t SP_OFF  = 0;                                  // 4 MB f32 sp table
    const size_t A_OFF   = (size_t)4 * 1024 * 1024;            // 1 MB bf16 a-frags
    const size_t KLP_OFF = (size_t)5 * 1024 * 1024;            // 4 KB kl_w partials
    const size_t W_OFF   = (size_t)5 * 1024 * 1024 + 65536;    // 64 MB bf16 weights
    const size_t NEED    = W_OFF + (size_t)B_ * OUT_ * IN_ * sizeof(__bf16);

    if (ws_size >= NEED) {
        float*  sp   = (float*)((char*)d_ws + SP_OFF);
        __bf16* a_ws = (__bf16*)((char*)d_ws + A_OFF);
        float*  klp  = (float*)((char*)d_ws + KLP_OFF);
        __bf16* w_ws = (__bf16*)((char*)d_ws + W_OFF);

        bpl_pre<<<1024, 256, 0, stream>>>(w_mu, w_eta, sp, klp);
        bpl_stage_a<<<32, 256, 0, stream>>>(input, a_ws);
        bpl_wgen<<<2048, 256, 0, stream>>>(w_mu, sp, eps_w, w_ws);
        bpl_gemm<<<2048, 256, 0, stream>>>(w_ws, a_ws, b_mu, b_eta, eps_b, out);
        bpl_klfin<<<1, 256, 0, stream>>>(klp, b_mu, b_eta, kl);
    } else {
        hipMemsetAsync(kl, 0, 2 * sizeof(float), stream);
        bpl_pre_fb<<<1024, 256, 0, stream>>>(w_mu, w_eta, b_mu, b_eta, kl);
        bpl_mfma_fb<<<512, 256, 0, stream>>>(input, w_mu, w_eta, b_mu, b_eta,
                                             eps_w, eps_b, out);
    }
}

// Round 9
// 48.869 us; speedup vs baseline: 1.5697x; 1.2693x over previous
//
#include <hip/hip_runtime.h>

// BayesPosLinear, fused MFMA with packed-table on-the-fly weights:
//   out[s,b,o] = sum_i input[s,b,i] * exp(w_mu[o,i] + (1e-6+softplus(w_std_eta[o,i]))*eps_w[b,o,i])
//                + (b_mu[o] + (1e-6+softplus(b_std_eta[o]))*eps_b[b,o])
//   + KL(w), KL(b).
// S=16, B=32, IN=1024, OUT=1024.
//
// R9: eliminate R8's 64MB w round-trip (~128MB traffic ~25us). Fuse w-gen into the
// MFMA GEMM; make one k-step register-resident:
//  - packed table tbl[o,i] (u32): hi16 = bf16(exp(w_mu)), lo16 = bf16((softplus+1e-6)*log2e)
//    -> w = emu * exp2(spl * eps). 5 loads/k-step (2 tbl + 2 eps + 1 a-frag).
//  - __launch_bounds__(256,4): 128-VGPR cap (R7's (256,8)/64-VGPR serialized every load).
//  - geometry/reduce/epilogue = R7/R8 verified K-split-4 kernel.
// Kernels: pre_pack (tbl + klw partials) -> stage_a -> fused -> klfin. ws ~5.1MB.

constexpr int S_ = 16, B_ = 32, IN_ = 1024, OUT_ = 1024;

typedef __bf16 bf16x8 __attribute__((ext_vector_type(8)));
typedef float  f32x4  __attribute__((ext_vector_type(4)));

__device__ __forceinline__ float softplus_f(float x) {
    float e = __expf(-fabsf(x));
    return fmaxf(x, 0.0f) + __logf(1.0f + e);
}

__device__ __forceinline__ unsigned bf16_hi(float x) {   // RNE-ish to high 16 bits
    return (__float_as_uint(x) + 0x8000u) & 0xffff0000u;
}

// ---------------- K1: packed table + kl_w per-block partials ----------------
__global__ __launch_bounds__(256) void bpl_pre_pack(
    const float* __restrict__ w_mu, const float* __restrict__ w_eta,
    unsigned* __restrict__ tbl,     // [OUT,IN] u32 packed (emu, spl)
    float* __restrict__ klw_part)   // [1024]
{
    __shared__ float red[4];
    const int tid  = threadIdx.x;
    const int wid  = tid >> 6;
    const int lane = tid & 63;

    const size_t base = (size_t)blockIdx.x * IN_ + tid * 4;
    const float4 mu = *reinterpret_cast<const float4*>(&w_mu[base]);
    const float4 et = *reinterpret_cast<const float4*>(&w_eta[base]);
    const float m[4] = {mu.x, mu.y, mu.z, mu.w};
    const float e[4] = {et.x, et.y, et.z, et.w};

    uint4 pk;
    unsigned* pku = &pk.x;
    float local = 0.0f;
    #pragma unroll
    for (int j = 0; j < 4; ++j) {
        const float sp  = __logf(1.0f + __expf(e[j])) + 1e-6f;  // w_eta in [-4,-2]
        const float spl = sp * 1.44269504f;                      // *log2(e)
        const float emu = __expf(m[j]);
        pku[j] = bf16_hi(emu) | (bf16_hi(spl) >> 16);
        local += -__logf(sp) + 0.5f * fmaf(sp, sp, m[j] * m[j]) - 0.5f;
    }
    *reinterpret_cast<uint4*>(&tbl[base]) = pk;

    #pragma unroll
    for (int off = 32; off > 0; off >>= 1) local += __shfl_xor(local, off, 64);
    if (lane == 0) red[wid] = local;
    __syncthreads();
    if (tid == 0) klw_part[blockIdx.x] = red[0] + red[1] + red[2] + red[3];
}

// ---------------- K0: input -> bf16 A-frags (R7/R8, verified) ----------------
__global__ __launch_bounds__(256) void bpl_stage_a(
    const float* __restrict__ input,   // [S,B,IN]
    __bf16* __restrict__ a_ws)         // [B][2048][8]
{
    const int b   = blockIdx.x;
    const int tid = threadIdx.x;
    #pragma unroll
    for (int j = 0; j < 8; ++j) {
        const int c  = tid + j * 256;
        const int s  = c & 15;
        const int k0 = ((c >> 6) << 5) | (((c >> 4) & 3) << 3);   // kt*32 + kg*8
        const float* src = input + ((size_t)s * B_ + b) * IN_ + k0;
        const float4 x0 = *reinterpret_cast<const float4*>(src);
        const float4 x1 = *reinterpret_cast<const float4*>(src + 4);
        bf16x8 v;
        v[0] = (__bf16)x0.x; v[1] = (__bf16)x0.y; v[2] = (__bf16)x0.z; v[3] = (__bf16)x0.w;
        v[4] = (__bf16)x1.x; v[5] = (__bf16)x1.y; v[6] = (__bf16)x1.z; v[7] = (__bf16)x1.w;
        *reinterpret_cast<bf16x8*>(&a_ws[(size_t)b * 16384 + (size_t)c * 8]) = v;
    }
}

// ---------------- K2: fused w-gen + K-split-4 MFMA GEMM ----------------
// 2048 blocks (xcd=blk&7; b=(blk>>3)&31; ot=blk>>8), 256 thr = 4 waves (K-quarters).
__global__ __launch_bounds__(256, 4) void bpl_fused(
    const unsigned* __restrict__ tbl,  // [OUT,IN] packed
    const __bf16* __restrict__ a_ws,   // [B][2048][8]
    const float* __restrict__ eps_w,   // [B,OUT,IN]
    const float* __restrict__ b_mu,    // [OUT]
    const float* __restrict__ b_eta,   // [OUT]
    const float* __restrict__ eps_b,   // [B,OUT]
    float* __restrict__ out)           // [S,B,OUT]
{
    __shared__ __align__(16) float red[4 * 64 * 4];   // [kq][lane][rr], 4KB

    const int blk = blockIdx.x;
    const int xcd = blk & 7;
    const int r_  = blk >> 3;          // 0..255
    const int b   = r_ & 31;
    const int ot  = r_ >> 5;           // 0..7
    const int o_base = xcd * 128 + ot * 16;

    const int tid  = threadIdx.x;
    const int kq   = tid >> 6;         // 0..3: K-quarter
    const int lane = tid & 63;
    const int on   = lane & 15;
    const int kg0  = lane >> 4;        // 0..3
    const int o_row = o_base + on;

    const int kbase = kq * 256 + kg0 * 8;
    const unsigned* __restrict__ tp = tbl + (size_t)o_row * IN_ + kbase;
    const float* __restrict__ ep = eps_w + ((size_t)b * OUT_ + o_row) * IN_ + kbase;
    const __bf16* __restrict__ ap = a_ws + (size_t)b * 16384 + (size_t)kq * 4096 + lane * 8;

    f32x4 acc = {0.0f, 0.0f, 0.0f, 0.0f};

    #pragma unroll
    for (int t = 0; t < 8; ++t) {
        const uint4  u0 = *reinterpret_cast<const uint4*>(tp + t * 32);
        const uint4  u1 = *reinterpret_cast<const uint4*>(tp + t * 32 + 4);
        const float4 e0 = *reinterpret_cast<const float4*>(ep + t * 32);
        const float4 e1 = *reinterpret_cast<const float4*>(ep + t * 32 + 4);
        const bf16x8 af = *reinterpret_cast<const bf16x8*>(ap + t * 512);

        const unsigned uu[8] = {u0.x, u0.y, u0.z, u0.w, u1.x, u1.y, u1.z, u1.w};
        const float    ee[8] = {e0.x, e0.y, e0.z, e0.w, e1.x, e1.y, e1.z, e1.w};

        bf16x8 bfrag;
        #pragma unroll
        for (int q = 0; q < 8; ++q) {
            const float emu = __uint_as_float(uu[q] & 0xffff0000u);
            const float spl = __uint_as_float(uu[q] << 16);
            bfrag[q] = (__bf16)(emu * exp2f(spl * ee[q]));
        }
        acc = __builtin_amdgcn_mfma_f32_16x16x32_bf16(af, bfrag, acc, 0, 0, 0);
    }

    *reinterpret_cast<f32x4*>(&red[(kq * 64 + lane) * 4]) = acc;
    __syncthreads();

    // thread tid -> (s = tid>>4, o = o_base + (tid&15)); sum the 4 K-quarters.
    {
        const int s  = tid >> 4;
        const int ol = tid & 15;
        const int srcLane = ((s >> 2) << 4) | ol;
        const int rr = s & 3;
        float v = red[(0 * 64 + srcLane) * 4 + rr] + red[(1 * 64 + srcLane) * 4 + rr]
                + red[(2 * 64 + srcLane) * 4 + rr] + red[(3 * 64 + srcLane) * 4 + rr];
        const int oo = o_base + ol;
        const float bias = fmaf(softplus_f(b_eta[oo]) + 1e-6f,
                                eps_b[(size_t)b * OUT_ + oo], b_mu[oo]);
        out[((size_t)s * B_ + b) * OUT_ + oo] = v + bias;
    }
}

// ---------------- K3: finalize both KLs (1 block, no atomics) ----------------
__global__ __launch_bounds__(256) void bpl_klfin(
    const float* __restrict__ klw_part,   // [1024]
    const float* __restrict__ b_mu, const float* __restrict__ b_eta,
    float* __restrict__ kl)               // kl[0]=kl_w, kl[1]=kl_b
{
    __shared__ float red[8];
    const int tid  = threadIdx.x;
    const int wid  = tid >> 6;
    const int lane = tid & 63;

    float lw = klw_part[tid] + klw_part[tid + 256]
             + klw_part[tid + 512] + klw_part[tid + 768];

    float lb = 0.0f;
    #pragma unroll
    for (int h = 0; h < 4; ++h) {
        const int o = tid + h * 256;
        const float sd = softplus_f(b_eta[o]) + 1e-6f;
        const float mm = b_mu[o];
        lb += -__logf(sd) + 0.5f * fmaf(sd, sd, mm * mm) - 0.5f;
    }

    #pragma unroll
    for (int off = 32; off > 0; off >>= 1) {
        lw += __shfl_xor(lw, off, 64);
        lb += __shfl_xor(lb, off, 64);
    }
    if (lane == 0) { red[wid] = lw; red[4 + wid] = lb; }
    __syncthreads();
    if (tid == 0) {
        kl[0] = red[0] + red[1] + red[2] + red[3];
        kl[1] = red[4] + red[5] + red[6] + red[7];
    }
}

// ---------------- fallback (R6/R7 verified path, no ws) ----------------
__global__ __launch_bounds__(256) void bpl_pre_fb(
    const float* __restrict__ w_mu, const float* __restrict__ w_eta,
    const float* __restrict__ b_mu, const float* __restrict__ b_eta,
    float* __restrict__ kl)
{
    __shared__ float red[4];
    const int tid  = threadIdx.x;
    const int wid  = tid >> 6;
    const int lane = tid & 63;

    const size_t base = (size_t)blockIdx.x * IN_ + tid * 4;
    const float4 mu = *reinterpret_cast<const float4*>(&w_mu[base]);
    const float4 et = *reinterpret_cast<const float4*>(&w_eta[base]);
    const float m[4] = {mu.x, mu.y, mu.z, mu.w};
    const float e[4] = {et.x, et.y, et.z, et.w};

    float local = 0.0f;
    #pragma unroll
    for (int j = 0; j < 4; ++j) {
        const float sp = __logf(1.0f + __expf(e[j])) + 1e-6f;
        local += -__logf(sp) + 0.5f * fmaf(sp, sp, m[j] * m[j]) - 0.5f;
    }
    #pragma unroll
    for (int off = 32; off > 0; off >>= 1) local += __shfl_xor(local, off, 64);
    if (lane == 0) red[wid] = local;
    __syncthreads();
    if (tid == 0) atomicAdd(&kl[0], red[0] + red[1] + red[2] + red[3]);

    if (blockIdx.x != 0) return;
    float lb = 0.0f;
    #pragma unroll
    for (int j = 0; j < 4; ++j) {
        const int idx = tid * 4 + j;
        const float sd = softplus_f(b_eta[idx]) + 1e-6f;
        const float mm = b_mu[idx];
        lb += -__logf(sd) + 0.5f * fmaf(sd, sd, mm * mm) - 0.5f;
    }
    #pragma unroll
    for (int off = 32; off > 0; off >>= 1) lb += __shfl_xor(lb, off, 64);
    __syncthreads();
    if (lane == 0) red[wid] = lb;
    __syncthreads();
    if (tid == 0) atomicAdd(&kl[1], red[0] + red[1] + red[2] + red[3]);
}

__global__ __launch_bounds__(256, 4) void bpl_mfma_fb(
    const float* __restrict__ input, const float* __restrict__ w_mu,
    const float* __restrict__ w_eta, const float* __restrict__ b_mu,
    const float* __restrict__ b_eta, const float* __restrict__ eps_w,
    const float* __restrict__ eps_b, float* __restrict__ out)
{
    __shared__ __align__(16) __bf16 alds[16384];

    const int blk = blockIdx.x;
    const int xcd = blk & 7;
    const int r_  = blk >> 3;
    const int b   = r_ & 31;
    const int oh  = r_ >> 5;
    const int o_base = (xcd * 2 + oh) * 64;

    const int tid  = threadIdx.x;
    const int wid  = tid >> 6;
    const int lane = tid & 63;

    #pragma unroll
    for (int j = 0; j < 8; ++j) {
        const int c   = tid + j * 256;
        const int s   = c & 15;
        const int kgg = ((c >> 6) << 2) | ((c >> 4) & 3);
        const float* src = input + ((size_t)s * B_ + b) * IN_ + kgg * 8;
        const float4 x0 = *reinterpret_cast<const float4*>(src);
        const float4 x1 = *reinterpret_cast<const float4*>(src + 4);
        bf16x8 v;
        v[0] = (__bf16)x0.x; v[1] = (__bf16)x0.y; v[2] = (__bf16)x0.z; v[3] = (__bf16)x0.w;
        v[4] = (__bf16)x1.x; v[5] = (__bf16)x1.y; v[6] = (__bf16)x1.z; v[7] = (__bf16)x1.w;
        *reinterpret_cast<bf16x8*>(&alds[c * 8]) = v;
    }
    __syncthreads();

    const int on    = lane & 15;
    const int kg0   = lane >> 4;
    const int o_row = o_base + wid * 16 + on;

    const float* __restrict__ mu_p = w_mu  + (size_t)o_row * IN_ + kg0 * 8;
    const float* __restrict__ et_p = w_eta + (size_t)o_row * IN_ + kg0 * 8;
    const float* __restrict__ ep_p = eps_w + ((size_t)b * OUT_ + o_row) * IN_ + kg0 * 8;
    const __bf16* __restrict__ a_p = alds + lane * 8;

    f32x4 acc = {0.0f, 0.0f, 0.0f, 0.0f};
    #pragma unroll
    for (int kt = 0; kt < 32; ++kt) {
        const int i_ = kt * 32;
        const float4 m0 = *reinterpret_cast<const float4*>(mu_p + i_);
        const float4 m1 = *reinterpret_cast<const float4*>(mu_p + i_ + 4);
        const float4 s0 = *reinterpret_cast<const float4*>(et_p + i_);
        const float4 s1 = *reinterpret_cast<const float4*>(et_p + i_ + 4);
        const float4 e0 = *reinterpret_cast<const float4*>(ep_p + i_);
        const float4 e1 = *reinterpret_cast<const float4*>(ep_p + i_ + 4);
        const float mm[8] = {m0.x, m0.y, m0.z, m0.w, m1.x, m1.y, m1.z, m1.w};
        const float ss[8] = {s0.x, s0.y, s0.z, s0.w, s1.x, s1.y, s1.z, s1.w};
        const float ee[8] = {e0.x, e0.y, e0.z, e0.w, e1.x, e1.y, e1.z, e1.w};
        bf16x8 bfrag;
        #pragma unroll
        for (int q = 0; q < 8; ++q) {
            const float sp_ = __logf(1.0f + __expf(ss[q])) + 1e-6f;
            bfrag[q] = (__bf16)__expf(fmaf(sp_, ee[q], mm[q]));
        }
        const bf16x8 afrag = *reinterpret_cast<const bf16x8*>(a_p + kt * 512);
        acc = __builtin_amdgcn_mfma_f32_16x16x32_bf16(afrag, bfrag, acc, 0, 0, 0);
    }

    const float bias = fmaf(softplus_f(b_eta[o_row]) + 1e-6f,
                            eps_b[(size_t)b * OUT_ + o_row], b_mu[o_row]);
    #pragma unroll
    for (int rr = 0; rr < 4; ++rr) {
        const int s = kg0 * 4 + rr;
        out[((size_t)s * B_ + b) * OUT_ + o_row] = acc[rr] + bias;
    }
}

extern "C" void kernel_launch(void* const* d_in, const int* in_sizes, int n_in,
                              void* d_out, int out_size, void* d_ws, size_t ws_size,
                              hipStream_t stream)
{
    const float* input = (const float*)d_in[0];
    const float* w_mu  = (const float*)d_in[1];
    const float* w_eta = (const float*)d_in[2];
    const float* b_mu  = (const float*)d_in[3];
    const float* b_eta = (const float*)d_in[4];
    const float* eps_w = (const float*)d_in[5];
    const float* eps_b = (const float*)d_in[6];

    float* out = (float*)d_out;
    float* kl  = out + (size_t)S_ * B_ * OUT_;   // offsets 524288, 524289

    // ws layout
    const size_t TBL_OFF = 0;                                  // 4 MB u32 packed table
    const size_t A_OFF   = (size_t)4 * 1024 * 1024;            // 1 MB bf16 a-frags
    const size_t KLP_OFF = (size_t)5 * 1024 * 1024;            // 4 KB kl_w partials
    const size_t NEED    = KLP_OFF + 4096;

    if (ws_size >= NEED) {
        unsigned* tbl  = (unsigned*)((char*)d_ws + TBL_OFF);
        __bf16*   a_ws = (__bf16*)((char*)d_ws + A_OFF);
        float*    klp  = (float*)((char*)d_ws + KLP_OFF);

        bpl_pre_pack<<<1024, 256, 0, stream>>>(w_mu, w_eta, tbl, klp);
        bpl_stage_a<<<32, 256, 0, stream>>>(input, a_ws);
        bpl_fused<<<2048, 256, 0, stream>>>(tbl, a_ws, eps_w, b_mu, b_eta, eps_b, out);
        bpl_klfin<<<1, 256, 0, stream>>>(klp, b_mu, b_eta, kl);
    } else {
        hipMemsetAsync(kl, 0, 2 * sizeof(float), stream);
        bpl_pre_fb<<<1024, 256, 0, stream>>>(w_mu, w_eta, b_mu, b_eta, kl);
        bpl_mfma_fb<<<512, 256, 0, stream>>>(input, w_mu, w_eta, b_mu, b_eta,
                                             eps_w, eps_b, out);
    }
}

// Round 10
// 43.906 us; speedup vs baseline: 1.7472x; 1.1130x over previous
//
#include <hip/hip_runtime.h>

// BayesPosLinear, fused MFMA + packed table + 4-deep prefetch, 2 launches total:
//   out[s,b,o] = sum_i input[s,b,i] * exp(w_mu[o,i] + (1e-6+softplus(w_std_eta[o,i]))*eps_w[b,o,i])
//                + (b_mu[o] + (1e-6+softplus(b_std_eta[o]))*eps_b[b,o])
//   + KL(w), KL(b).
// S=16, B=32, IN=1024, OUT=1024.
//
// R10 (from R9's 48.9us):
//  - Launch merge: K1 = pre2 (1056 blocks: 0-1023 tbl+klw partials, 1024-1055 A-frags);
//    K2 = fused (2049 blocks: 0-2047 GEMM, 2048 klfin). No memset, no atomics.
//  - fused inner loop: 4-deep static prefetch (buffers indexed t&3, fully unrolled ->
//    static indices). Prologue issues 4 k-steps of loads back-to-back; steady state
//    issues step t+4's 5 loads right after consuming step t. ~105 VGPR under (256,4).
//  - table u32 = (bf16 exp(w_mu) | bf16 (softplus+1e-6)*log2e); w = emu*exp2(spl*eps).

constexpr int S_ = 16, B_ = 32, IN_ = 1024, OUT_ = 1024;

typedef __bf16 bf16x8 __attribute__((ext_vector_type(8)));
typedef float  f32x4  __attribute__((ext_vector_type(4)));

__device__ __forceinline__ float softplus_f(float x) {
    float e = __expf(-fabsf(x));
    return fmaxf(x, 0.0f) + __logf(1.0f + e);
}

__device__ __forceinline__ unsigned bf16_hi(float x) {   // round-to-nearest-ish, keep high 16
    return (__float_as_uint(x) + 0x8000u) & 0xffff0000u;
}

// ---------------- K1: packed table + klw partials (blocks 0-1023) ----------------
//                    input -> bf16 A-frags        (blocks 1024-1055)
__global__ __launch_bounds__(256) void bpl_pre2(
    const float* __restrict__ input,   // [S,B,IN]
    const float* __restrict__ w_mu, const float* __restrict__ w_eta,
    unsigned* __restrict__ tbl,        // [OUT,IN] u32 packed (emu, spl)
    __bf16* __restrict__ a_ws,         // [B][2048][8]
    float* __restrict__ klw_part)      // [1024]
{
    const int tid = threadIdx.x;

    if (blockIdx.x >= 1024) {          // ---- A-frag staging (R7/R8 verified) ----
        const int b = blockIdx.x - 1024;
        #pragma unroll
        for (int j = 0; j < 8; ++j) {
            const int c  = tid + j * 256;
            const int k0 = ((c >> 6) << 5) | (((c >> 4) & 3) << 3);   // kt*32 + kg*8
            const int s  = c & 15;
            const float* src = input + ((size_t)s * B_ + b) * IN_ + k0;
            const float4 x0 = *reinterpret_cast<const float4*>(src);
            const float4 x1 = *reinterpret_cast<const float4*>(src + 4);
            bf16x8 v;
            v[0] = (__bf16)x0.x; v[1] = (__bf16)x0.y; v[2] = (__bf16)x0.z; v[3] = (__bf16)x0.w;
            v[4] = (__bf16)x1.x; v[5] = (__bf16)x1.y; v[6] = (__bf16)x1.z; v[7] = (__bf16)x1.w;
            *reinterpret_cast<bf16x8*>(&a_ws[(size_t)b * 16384 + (size_t)c * 8]) = v;
        }
        return;
    }

    __shared__ float red[4];
    const int wid  = tid >> 6;
    const int lane = tid & 63;

    const size_t base = (size_t)blockIdx.x * IN_ + tid * 4;
    const float4 mu = *reinterpret_cast<const float4*>(&w_mu[base]);
    const float4 et = *reinterpret_cast<const float4*>(&w_eta[base]);
    const float m[4] = {mu.x, mu.y, mu.z, mu.w};
    const float e[4] = {et.x, et.y, et.z, et.w};

    uint4 pk;
    unsigned* pku = &pk.x;
    float local = 0.0f;
    #pragma unroll
    for (int j = 0; j < 4; ++j) {
        const float sp  = __logf(1.0f + __expf(e[j])) + 1e-6f;  // w_eta in [-4,-2]
        const float spl = sp * 1.44269504f;                      // *log2(e)
        const float emu = __expf(m[j]);
        pku[j] = bf16_hi(emu) | (bf16_hi(spl) >> 16);
        local += -__logf(sp) + 0.5f * fmaf(sp, sp, m[j] * m[j]) - 0.5f;
    }
    *reinterpret_cast<uint4*>(&tbl[base]) = pk;

    #pragma unroll
    for (int off = 32; off > 0; off >>= 1) local += __shfl_xor(local, off, 64);
    if (lane == 0) red[wid] = local;
    __syncthreads();
    if (tid == 0) klw_part[blockIdx.x] = red[0] + red[1] + red[2] + red[3];
}

// ---------------- K2: fused w-gen + K-split-4 MFMA GEMM + klfin ----------------
// blocks 0-2047: GEMM (xcd=blk&7; b=(blk>>3)&31; ot=blk>>8), 256 thr = 4 kq-waves.
// block 2048   : finalize both KLs from klw_part (no atomics).
__global__ __launch_bounds__(256, 4) void bpl_fused(
    const unsigned* __restrict__ tbl,  // [OUT,IN] packed
    const __bf16* __restrict__ a_ws,   // [B][2048][8]
    const float* __restrict__ eps_w,   // [B,OUT,IN]
    const float* __restrict__ b_mu,    // [OUT]
    const float* __restrict__ b_eta,   // [OUT]
    const float* __restrict__ eps_b,   // [B,OUT]
    const float* __restrict__ klw_part,// [1024]
    float* __restrict__ out,           // [S,B,OUT]
    float* __restrict__ kl)            // kl[0], kl[1]
{
    const int blk = blockIdx.x;
    const int tid = threadIdx.x;

    if (blk == 2048) {                 // ---- klfin ----
        __shared__ float kred[8];
        const int wid  = tid >> 6;
        const int lane = tid & 63;
        float lw = klw_part[tid] + klw_part[tid + 256]
                 + klw_part[tid + 512] + klw_part[tid + 768];
        float lb = 0.0f;
        #pragma unroll
        for (int h = 0; h < 4; ++h) {
            const int o = tid + h * 256;
            const float sd = softplus_f(b_eta[o]) + 1e-6f;
            const float mm = b_mu[o];
            lb += -__logf(sd) + 0.5f * fmaf(sd, sd, mm * mm) - 0.5f;
        }
        #pragma unroll
        for (int off = 32; off > 0; off >>= 1) {
            lw += __shfl_xor(lw, off, 64);
            lb += __shfl_xor(lb, off, 64);
        }
        if (lane == 0) { kred[wid] = lw; kred[4 + wid] = lb; }
        __syncthreads();
        if (tid == 0) {
            kl[0] = kred[0] + kred[1] + kred[2] + kred[3];
            kl[1] = kred[4] + kred[5] + kred[6] + kred[7];
        }
        return;
    }

    __shared__ __align__(16) float red[4 * 64 * 4];   // [kq][lane][rr], 4KB

    const int xcd = blk & 7;
    const int r_  = blk >> 3;          // 0..255
    const int b   = r_ & 31;
    const int ot  = r_ >> 5;           // 0..7
    const int o_base = xcd * 128 + ot * 16;

    const int kq   = tid >> 6;         // 0..3: K-quarter
    const int lane = tid & 63;
    const int on   = lane & 15;
    const int kg0  = lane >> 4;        // 0..3
    const int o_row = o_base + on;

    const int kbase = kq * 256 + kg0 * 8;
    const unsigned* __restrict__ tp = tbl + (size_t)o_row * IN_ + kbase;
    const float* __restrict__ ep = eps_w + ((size_t)b * OUT_ + o_row) * IN_ + kbase;
    const __bf16* __restrict__ ap = a_ws + (size_t)b * 16384 + (size_t)kq * 4096 + lane * 8;

    f32x4 acc = {0.0f, 0.0f, 0.0f, 0.0f};

    // ---- 4-deep static prefetch pipeline over the 8 k-steps ----
    uint4  tb0[4], tb1[4];
    float4 ev0[4], ev1[4];
    bf16x8 av[4];

#define BPL_LD(T) do {                                                                    \
        ev0[(T) & 3] = *reinterpret_cast<const float4*>(ep + (T) * 32);                   \
        ev1[(T) & 3] = *reinterpret_cast<const float4*>(ep + (T) * 32 + 4);               \
        tb0[(T) & 3] = *reinterpret_cast<const uint4*>(tp + (T) * 32);                    \
        tb1[(T) & 3] = *reinterpret_cast<const uint4*>(tp + (T) * 32 + 4);                \
        av[(T) & 3]  = *reinterpret_cast<const bf16x8*>(ap + (T) * 512); } while (0)

    BPL_LD(0); BPL_LD(1); BPL_LD(2); BPL_LD(3);

    #pragma unroll
    for (int t = 0; t < 8; ++t) {
        const uint4  u0 = tb0[t & 3], u1 = tb1[t & 3];
        const float4 e0 = ev0[t & 3], e1 = ev1[t & 3];
        const bf16x8 af = av[t & 3];

        const unsigned uu[8] = {u0.x, u0.y, u0.z, u0.w, u1.x, u1.y, u1.z, u1.w};
        const float    ee[8] = {e0.x, e0.y, e0.z, e0.w, e1.x, e1.y, e1.z, e1.w};

        bf16x8 bfrag;
        #pragma unroll
        for (int q = 0; q < 8; ++q) {
            const float emu = __uint_as_float(uu[q] & 0xffff0000u);
            const float spl = __uint_as_float(uu[q] << 16);
            bfrag[q] = (__bf16)(emu * exp2f(spl * ee[q]));
        }

        if (t < 4) BPL_LD(t + 4);      // issue next slot's loads before the MFMA

        acc = __builtin_amdgcn_mfma_f32_16x16x32_bf16(af, bfrag, acc, 0, 0, 0);
    }
#undef BPL_LD

    *reinterpret_cast<f32x4*>(&red[(kq * 64 + lane) * 4]) = acc;
    __syncthreads();

    // thread tid -> (s = tid>>4, o = o_base + (tid&15)); sum the 4 K-quarters.
    {
        const int s  = tid >> 4;
        const int ol = tid & 15;
        const int srcLane = ((s >> 2) << 4) | ol;
        const int rr = s & 3;
        float v = red[(0 * 64 + srcLane) * 4 + rr] + red[(1 * 64 + srcLane) * 4 + rr]
                + red[(2 * 64 + srcLane) * 4 + rr] + red[(3 * 64 + srcLane) * 4 + rr];
        const int oo = o_base + ol;
        const float bias = fmaf(softplus_f(b_eta[oo]) + 1e-6f,
                                eps_b[(size_t)b * OUT_ + oo], b_mu[oo]);
        out[((size_t)s * B_ + b) * OUT_ + oo] = v + bias;
    }
}

// ---------------- fallback (R6/R7 verified path, no ws) ----------------
__global__ __launch_bounds__(256) void bpl_pre_fb(
    const float* __restrict__ w_mu, const float* __restrict__ w_eta,
    const float* __restrict__ b_mu, const float* __restrict__ b_eta,
    float* __restrict__ kl)
{
    __shared__ float red[4];
    const int tid  = threadIdx.x;
    const int wid  = tid >> 6;
    const int lane = tid & 63;

    const size_t base = (size_t)blockIdx.x * IN_ + tid * 4;
    const float4 mu = *reinterpret_cast<const float4*>(&w_mu[base]);
    const float4 et = *reinterpret_cast<const float4*>(&w_eta[base]);
    const float m[4] = {mu.x, mu.y, mu.z, mu.w};
    const float e[4] = {et.x, et.y, et.z, et.w};

    float local = 0.0f;
    #pragma unroll
    for (int j = 0; j < 4; ++j) {
        const float sp = __logf(1.0f + __expf(e[j])) + 1e-6f;
        local += -__logf(sp) + 0.5f * fmaf(sp, sp, m[j] * m[j]) - 0.5f;
    }
    #pragma unroll
    for (int off = 32; off > 0; off >>= 1) local += __shfl_xor(local, off, 64);
    if (lane == 0) red[wid] = local;
    __syncthreads();
    if (tid == 0) atomicAdd(&kl[0], red[0] + red[1] + red[2] + red[3]);

    if (blockIdx.x != 0) return;
    float lb = 0.0f;
    #pragma unroll
    for (int j = 0; j < 4; ++j) {
        const int idx = tid * 4 + j;
        const float sd = softplus_f(b_eta[idx]) + 1e-6f;
        const float mm = b_mu[idx];
        lb += -__logf(sd) + 0.5f * fmaf(sd, sd, mm * mm) - 0.5f;
    }
    #pragma unroll
    for (int off = 32; off > 0; off >>= 1) lb += __shfl_xor(lb, off, 64);
    __syncthreads();
    if (lane == 0) red[wid] = lb;
    __syncthreads();
    if (tid == 0) atomicAdd(&kl[1], red[0] + red[1] + red[2] + red[3]);
}

__global__ __launch_bounds__(256, 4) void bpl_mfma_fb(
    const float* __restrict__ input, const float* __restrict__ w_mu,
    const float* __restrict__ w_eta, const float* __restrict__ b_mu,
    const float* __restrict__ b_eta, const float* __restrict__ eps_w,
    const float* __restrict__ eps_b, float* __restrict__ out)
{
    __shared__ __align__(16) __bf16 alds[16384];

    const int blk = blockIdx.x;
    const int xcd = blk & 7;
    const int r_  = blk >> 3;
    const int b   = r_ & 31;
    const int oh  = r_ >> 5;
    const int o_base = (xcd * 2 + oh) * 64;

    const int tid  = threadIdx.x;
    const int wid  = tid >> 6;
    const int lane = tid & 63;

    #pragma unroll
    for (int j = 0; j < 8; ++j) {
        const int c   = tid + j * 256;
        const int s   = c & 15;
        const int kgg = ((c >> 6) << 2) | ((c >> 4) & 3);
        const float* src = input + ((size_t)s * B_ + b) * IN_ + kgg * 8;
        const float4 x0 = *reinterpret_cast<const float4*>(src);
        const float4 x1 = *reinterpret_cast<const float4*>(src + 4);
        bf16x8 v;
        v[0] = (__bf16)x0.x; v[1] = (__bf16)x0.y; v[2] = (__bf16)x0.z; v[3] = (__bf16)x0.w;
        v[4] = (__bf16)x1.x; v[5] = (__bf16)x1.y; v[6] = (__bf16)x1.z; v[7] = (__bf16)x1.w;
        *reinterpret_cast<bf16x8*>(&alds[c * 8]) = v;
    }
    __syncthreads();

    const int on    = lane & 15;
    const int kg0   = lane >> 4;
    const int o_row = o_base + wid * 16 + on;

    const float* __restrict__ mu_p = w_mu  + (size_t)o_row * IN_ + kg0 * 8;
    const float* __restrict__ et_p = w_eta + (size_t)o_row * IN_ + kg0 * 8;
    const float* __restrict__ ep_p = eps_w + ((size_t)b * OUT_ + o_row) * IN_ + kg0 * 8;
    const __bf16* __restrict__ a_p = alds + lane * 8;

    f32x4 acc = {0.0f, 0.0f, 0.0f, 0.0f};
    #pragma unroll
    for (int kt = 0; kt < 32; ++kt) {
        const int i_ = kt * 32;
        const float4 m0 = *reinterpret_cast<const float4*>(mu_p + i_);
        const float4 m1 = *reinterpret_cast<const float4*>(mu_p + i_ + 4);
        const float4 s0 = *reinterpret_cast<const float4*>(et_p + i_);
        const float4 s1 = *reinterpret_cast<const float4*>(et_p + i_ + 4);
        const float4 e0 = *reinterpret_cast<const float4*>(ep_p + i_);
        const float4 e1 = *reinterpret_cast<const float4*>(ep_p + i_ + 4);
        const float mm[8] = {m0.x, m0.y, m0.z, m0.w, m1.x, m1.y, m1.z, m1.w};
        const float ss[8] = {s0.x, s0.y, s0.z, s0.w, s1.x, s1.y, s1.z, s1.w};
        const float ee[8] = {e0.x, e0.y, e0.z, e0.w, e1.x, e1.y, e1.z, e1.w};
        bf16x8 bfrag;
        #pragma unroll
        for (int q = 0; q < 8; ++q) {
            const float sp_ = __logf(1.0f + __expf(ss[q])) + 1e-6f;
            bfrag[q] = (__bf16)__expf(fmaf(sp_, ee[q], mm[q]));
        }
        const bf16x8 afrag = *reinterpret_cast<const bf16x8*>(a_p + kt * 512);
        acc = __builtin_amdgcn_mfma_f32_16x16x32_bf16(afrag, bfrag, acc, 0, 0, 0);
    }

    const float bias = fmaf(softplus_f(b_eta[o_row]) + 1e-6f,
                            eps_b[(size_t)b * OUT_ + o_row], b_mu[o_row]);
    #pragma unroll
    for (int rr = 0; rr < 4; ++rr) {
        const int s = kg0 * 4 + rr;
        out[((size_t)s * B_ + b) * OUT_ + o_row] = acc[rr] + bias;
    }
}

extern "C" void kernel_launch(void* const* d_in, const int* in_sizes, int n_in,
                              void* d_out, int out_size, void* d_ws, size_t ws_size,
                              hipStream_t stream)
{
    const float* input = (const float*)d_in[0];
    const float* w_mu  = (const float*)d_in[1];
    const float* w_eta = (const float*)d_in[2];
    const float* b_mu  = (const float*)d_in[3];
    const float* b_eta = (const float*)d_in[4];
    const float* eps_w = (const float*)d_in[5];
    const float* eps_b = (const float*)d_in[6];

    float* out = (float*)d_out;
    float* kl  = out + (size_t)S_ * B_ * OUT_;   // offsets 524288, 524289

    // ws layout
    const size_t TBL_OFF = 0;                                  // 4 MB u32 packed table
    const size_t A_OFF   = (size_t)4 * 1024 * 1024;            // 1 MB bf16 a-frags
    const size_t KLP_OFF = (size_t)5 * 1024 * 1024;            // 4 KB kl_w partials
    const size_t NEED    = KLP_OFF + 4096;

    if (ws_size >= NEED) {
        unsigned* tbl  = (unsigned*)((char*)d_ws + TBL_OFF);
        __bf16*   a_ws = (__bf16*)((char*)d_ws + A_OFF);
        float*    klp  = (float*)((char*)d_ws + KLP_OFF);

        bpl_pre2<<<1056, 256, 0, stream>>>(input, w_mu, w_eta, tbl, a_ws, klp);
        bpl_fused<<<2049, 256, 0, stream>>>(tbl, a_ws, eps_w, b_mu, b_eta, eps_b,
                                            klp, out, kl);
    } else {
        hipMemsetAsync(kl, 0, 2 * sizeof(float), stream);
        bpl_pre_fb<<<1024, 256, 0, stream>>>(w_mu, w_eta, b_mu, b_eta, kl);
        bpl_mfma_fb<<<512, 256, 0, stream>>>(input, w_mu, w_eta, b_mu, b_eta,
                                             eps_w, eps_b, out);
    }
}

// Round 11
// 37.692 us; speedup vs baseline: 2.0353x; 1.1649x over previous
//
#include <hip/hip_runtime.h>

// BayesPosLinear, fully-coalesced fused MFMA:
//   out[s,b,o] = sum_i input[s,b,i] * exp(w_mu[o,i] + (1e-6+softplus(w_std_eta[o,i]))*eps_w[b,o,i])
//                + (b_mu[o] + (1e-6+softplus(b_std_eta[o]))*eps_b[b,o])
//   + KL(w), KL(b).
// S=16, B=32, IN=1024, OUT=1024.
//
// R11 (from R10's 43.9us): kill address divergence + expose full load ILP.
//  - tbl precomputed in MFMA-FRAG order (free permutation in prepass) -> k-loop tbl
//    reads are lane-contiguous (1KB/instr).
//  - a_ws already frag-ordered (R7+).
//  - eps: 512-thr blocks, K-split-8. Wave owns [16 rows x 128 k] = 8KB: 16 coalesced
//    dwordx2 row loads -> XOR-swizzled LDS -> 4 k-steps read B-frags from LDS.
//  - ALL global loads (16 eps + 8 tbl + 4 a) issue up front; one barrier; k-loop is
//    pure reg/LDS/VALU/MFMA. (512,4): <=128 VGPR, 2 blocks/CU, 4 waves/SIMD.
//  - grid: 2049 blocks (2048 GEMM = 32b x 64 o-tiles; block 2048 = KL finalize).

constexpr int S_ = 16, B_ = 32, IN_ = 1024, OUT_ = 1024;

typedef __bf16 bf16x8 __attribute__((ext_vector_type(8)));
typedef float  f32x4  __attribute__((ext_vector_type(4)));

__device__ __forceinline__ float softplus_f(float x) {
    float e = __expf(-fabsf(x));
    return fmaxf(x, 0.0f) + __logf(1.0f + e);
}

__device__ __forceinline__ unsigned bf16_hi(float x) {   // round, keep high 16
    return (__float_as_uint(x) + 0x8000u) & 0xffff0000u;
}

// ---------------- K1: frag-ordered packed table + klw partials (blocks 0-1023) ----
//                     input -> bf16 A-frags (blocks 1024-1055)
// tbl_f layout: [ot(64)][kt(32)][lane(64)][8 u32]; lane = kg0*16 + on holds
// W-row (ot*16+on), k = kt*32 + kg0*8 + j.
__global__ __launch_bounds__(256) void bpl_pre2(
    const float* __restrict__ input,   // [S,B,IN]
    const float* __restrict__ w_mu, const float* __restrict__ w_eta,
    unsigned* __restrict__ tbl_f,      // 4MB frag-ordered
    __bf16* __restrict__ a_ws,         // [B][2048][8]
    float* __restrict__ klw_part)      // [1024]
{
    const int tid = threadIdx.x;

    if (blockIdx.x >= 1024) {          // ---- A-frag staging (verified R7+) ----
        const int b = blockIdx.x - 1024;
        #pragma unroll
        for (int j = 0; j < 8; ++j) {
            const int c  = tid + j * 256;
            const int k0 = ((c >> 6) << 5) | (((c >> 4) & 3) << 3);
            const int s  = c & 15;
            const float* src = input + ((size_t)s * B_ + b) * IN_ + k0;
            const float4 x0 = *reinterpret_cast<const float4*>(src);
            const float4 x1 = *reinterpret_cast<const float4*>(src + 4);
            bf16x8 v;
            v[0] = (__bf16)x0.x; v[1] = (__bf16)x0.y; v[2] = (__bf16)x0.z; v[3] = (__bf16)x0.w;
            v[4] = (__bf16)x1.x; v[5] = (__bf16)x1.y; v[6] = (__bf16)x1.z; v[7] = (__bf16)x1.w;
            *reinterpret_cast<bf16x8*>(&a_ws[(size_t)b * 16384 + (size_t)c * 8]) = v;
        }
        return;
    }

    __shared__ float red[4];
    const int wid  = tid >> 6;
    const int lane = tid & 63;
    const int o    = blockIdx.x;
    const int ot   = o >> 4;
    const int on   = o & 15;

    const size_t base = (size_t)o * IN_ + tid * 4;
    const float4 mu = *reinterpret_cast<const float4*>(&w_mu[base]);
    const float4 et = *reinterpret_cast<const float4*>(&w_eta[base]);
    const float m[4] = {mu.x, mu.y, mu.z, mu.w};
    const float e[4] = {et.x, et.y, et.z, et.w};

    float local = 0.0f;
    #pragma unroll
    for (int j = 0; j < 4; ++j) {
        const int   i   = tid * 4 + j;
        const float sp  = __logf(1.0f + __expf(e[j])) + 1e-6f;  // w_eta in [-4,-2]
        const float spl = sp * 1.44269504f;                      // *log2(e)
        const float emu = __expf(m[j]);
        const unsigned pk = bf16_hi(emu) | (bf16_hi(spl) >> 16);
        const int kt  = i >> 5;
        const int kg0 = (i >> 3) & 3;
        const int jj  = i & 7;
        const int ln  = kg0 * 16 + on;
        tbl_f[(((size_t)ot * 32 + kt) * 64 + ln) * 8 + jj] = pk;
        local += -__logf(sp) + 0.5f * fmaf(sp, sp, m[j] * m[j]) - 0.5f;
    }

    #pragma unroll
    for (int off = 32; off > 0; off >>= 1) local += __shfl_xor(local, off, 64);
    if (lane == 0) red[wid] = local;
    __syncthreads();
    if (tid == 0) klw_part[blockIdx.x] = red[0] + red[1] + red[2] + red[3];
}

// ---------------- K2: fused GEMM (blocks 0-2047) + klfin (block 2048) ----------
__global__ __launch_bounds__(512, 4) void bpl_fused(
    const unsigned* __restrict__ tbl_f,// frag-ordered table
    const __bf16* __restrict__ a_ws,   // [B][2048][8]
    const float* __restrict__ eps_w,   // [B,OUT,IN]
    const float* __restrict__ b_mu,    // [OUT]
    const float* __restrict__ b_eta,   // [OUT]
    const float* __restrict__ eps_b,   // [B,OUT]
    const float* __restrict__ klw_part,// [1024]
    float* __restrict__ out,           // [S,B,OUT]
    float* __restrict__ kl)            // kl[0], kl[1]
{
    const int blk = blockIdx.x;
    const int tid = threadIdx.x;

    if (blk == 2048) {                 // ---- klfin (512 threads) ----
        __shared__ float kred[16];
        const int wid  = tid >> 6;
        const int lane = tid & 63;
        float lw = klw_part[tid & 1023] * 0.0f;   // placate: compute real below
        lw = ((tid < 512) ? klw_part[tid] + klw_part[tid + 512] : 0.0f);
        float lb = 0.0f;
        {
            const int o = tid;               // 0..511
            const float sd0 = softplus_f(b_eta[o]) + 1e-6f;
            const float m0  = b_mu[o];
            const float sd1 = softplus_f(b_eta[o + 512]) + 1e-6f;
            const float m1  = b_mu[o + 512];
            lb = (-__logf(sd0) + 0.5f * fmaf(sd0, sd0, m0 * m0) - 0.5f)
               + (-__logf(sd1) + 0.5f * fmaf(sd1, sd1, m1 * m1) - 0.5f);
        }
        #pragma unroll
        for (int off = 32; off > 0; off >>= 1) {
            lw += __shfl_xor(lw, off, 64);
            lb += __shfl_xor(lb, off, 64);
        }
        if (lane == 0) { kred[wid] = lw; kred[8 + wid] = lb; }
        __syncthreads();
        if (tid == 0) {
            float tw = 0.0f, tb = 0.0f;
            #pragma unroll
            for (int k = 0; k < 8; ++k) { tw += kred[k]; tb += kred[8 + k]; }
            kl[0] = tw; kl[1] = tb;
        }
        return;
    }

    __shared__ __align__(16) float smem[16384];   // 64KB: 8 waves x 8KB eps; reused for reduce

    const int xcd = blk & 7;
    const int r_  = blk >> 3;          // 0..255
    const int b   = r_ & 31;
    const int otl = r_ >> 5;           // 0..7
    const int o_base = xcd * 128 + otl * 16;
    const int ot_g   = o_base >> 4;    // global o-tile 0..63

    const int kq   = tid >> 6;         // 0..7: K-eighth
    const int lane = tid & 63;
    const int on   = lane & 15;
    const int kg0  = lane >> 4;        // 0..3

    // ---- issue ALL global loads up front (coalesced) ----
    const float* eps_base = eps_w + ((size_t)(b * 1024 + o_base)) * 1024 + kq * 128;
    float2 ev[16];
    #pragma unroll
    for (int r = 0; r < 16; ++r)
        ev[r] = *reinterpret_cast<const float2*>(eps_base + (size_t)r * 1024 + lane * 2);

    const unsigned* tf = tbl_f + (((size_t)ot_g * 32 + kq * 4) * 64 + lane) * 8;
    uint4 t0[4], t1[4];
    #pragma unroll
    for (int t = 0; t < 4; ++t) {
        t0[t] = *reinterpret_cast<const uint4*>(tf + t * 512);
        t1[t] = *reinterpret_cast<const uint4*>(tf + t * 512 + 4);
    }

    const __bf16* ap = a_ws + (size_t)b * 16384 + (size_t)(kq * 4) * 512 + lane * 8;
    bf16x8 av[4];
    #pragma unroll
    for (int t = 0; t < 4; ++t)
        av[t] = *reinterpret_cast<const bf16x8*>(ap + t * 512);

    // ---- stage eps into wave-local LDS (8KB), XOR-swizzled rows ----
    char* wbase = (char*)(smem + kq * 2048);      // 8KB per wave
    #pragma unroll
    for (int r = 0; r < 16; ++r) {
        const int byte = (lane * 8) ^ ((r & 7) << 4);
        *reinterpret_cast<float2*>(wbase + r * 512 + byte) = ev[r];
    }
    __syncthreads();

    // ---- 4 k-steps: LDS B-frag + reg tbl/a -> MFMA ----
    f32x4 acc = {0.0f, 0.0f, 0.0f, 0.0f};
    const int sw = (on & 7) << 4;
    #pragma unroll
    for (int t = 0; t < 4; ++t) {
        const f32x4 e0 = *reinterpret_cast<const f32x4*>(
            wbase + on * 512 + (((t * 128 + kg0 * 32)) ^ sw));
        const f32x4 e1 = *reinterpret_cast<const f32x4*>(
            wbase + on * 512 + (((t * 128 + kg0 * 32 + 16)) ^ sw));

        const unsigned uu[8] = {t0[t].x, t0[t].y, t0[t].z, t0[t].w,
                                t1[t].x, t1[t].y, t1[t].z, t1[t].w};
        const float    ee[8] = {e0[0], e0[1], e0[2], e0[3], e1[0], e1[1], e1[2], e1[3]};

        bf16x8 bfrag;
        #pragma unroll
        for (int q = 0; q < 8; ++q) {
            const float emu = __uint_as_float(uu[q] & 0xffff0000u);
            const float spl = __uint_as_float(uu[q] << 16);
            bfrag[q] = (__bf16)(emu * exp2f(spl * ee[q]));
        }
        acc = __builtin_amdgcn_mfma_f32_16x16x32_bf16(av[t], bfrag, acc, 0, 0, 0);
    }

    // ---- reduce 8 K-partials via LDS (overlay on eps region) ----
    __syncthreads();                   // all eps reads done
    *reinterpret_cast<f32x4*>(&smem[(kq * 64 + lane) * 4]) = acc;
    __syncthreads();

    if (tid < 256) {
        const int s  = tid >> 4;       // 0..15
        const int ol = tid & 15;
        const int srcLane = ((s >> 2) << 4) | ol;
        const int rr = s & 3;
        float v = 0.0f;
        #pragma unroll
        for (int k8 = 0; k8 < 8; ++k8)
            v += smem[((k8 * 64 + srcLane) * 4) + rr];
        const int oo = o_base + ol;
        const float bias = fmaf(softplus_f(b_eta[oo]) + 1e-6f,
                                eps_b[(size_t)b * OUT_ + oo], b_mu[oo]);
        out[((size_t)s * B_ + b) * OUT_ + oo] = v + bias;
    }
}

// ---------------- fallback (R6/R7 verified path, no ws) ----------------
__global__ __launch_bounds__(256) void bpl_pre_fb(
    const float* __restrict__ w_mu, const float* __restrict__ w_eta,
    const float* __restrict__ b_mu, const float* __restrict__ b_eta,
    float* __restrict__ kl)
{
    __shared__ float red[4];
    const int tid  = threadIdx.x;
    const int wid  = tid >> 6;
    const int lane = tid & 63;

    const size_t base = (size_t)blockIdx.x * IN_ + tid * 4;
    const float4 mu = *reinterpret_cast<const float4*>(&w_mu[base]);
    const float4 et = *reinterpret_cast<const float4*>(&w_eta[base]);
    const float m[4] = {mu.x, mu.y, mu.z, mu.w};
    const float e[4] = {et.x, et.y, et.z, et.w};

    float local = 0.0f;
    #pragma unroll
    for (int j = 0; j < 4; ++j) {
        const float sp = __logf(1.0f + __expf(e[j])) + 1e-6f;
        local += -__logf(sp) + 0.5f * fmaf(sp, sp, m[j] * m[j]) - 0.5f;
    }
    #pragma unroll
    for (int off = 32; off > 0; off >>= 1) local += __shfl_xor(local, off, 64);
    if (lane == 0) red[wid] = local;
    __syncthreads();
    if (tid == 0) atomicAdd(&kl[0], red[0] + red[1] + red[2] + red[3]);

    if (blockIdx.x != 0) return;
    float lb = 0.0f;
    #pragma unroll
    for (int j = 0; j < 4; ++j) {
        const int idx = tid * 4 + j;
        const float sd = softplus_f(b_eta[idx]) + 1e-6f;
        const float mm = b_mu[idx];
        lb += -__logf(sd) + 0.5f * fmaf(sd, sd, mm * mm) - 0.5f;
    }
    #pragma unroll
    for (int off = 32; off > 0; off >>= 1) lb += __shfl_xor(lb, off, 64);
    __syncthreads();
    if (lane == 0) red[wid] = lb;
    __syncthreads();
    if (tid == 0) atomicAdd(&kl[1], red[0] + red[1] + red[2] + red[3]);
}

__global__ __launch_bounds__(256, 4) void bpl_mfma_fb(
    const float* __restrict__ input, const float* __restrict__ w_mu,
    const float* __restrict__ w_eta, const float* __restrict__ b_mu,
    const float* __restrict__ b_eta, const float* __restrict__ eps_w,
    const float* __restrict__ eps_b, float* __restrict__ out)
{
    __shared__ __align__(16) __bf16 alds[16384];

    const int blk = blockIdx.x;
    const int xcd = blk & 7;
    const int r_  = blk >> 3;
    const int b   = r_ & 31;
    const int oh  = r_ >> 5;
    const int o_base = (xcd * 2 + oh) * 64;

    const int tid  = threadIdx.x;
    const int wid  = tid >> 6;
    const int lane = tid & 63;

    #pragma unroll
    for (int j = 0; j < 8; ++j) {
        const int c   = tid + j * 256;
        const int s   = c & 15;
        const int kgg = ((c >> 6) << 2) | ((c >> 4) & 3);
        const float* src = input + ((size_t)s * B_ + b) * IN_ + kgg * 8;
        const float4 x0 = *reinterpret_cast<const float4*>(src);
        const float4 x1 = *reinterpret_cast<const float4*>(src + 4);
        bf16x8 v;
        v[0] = (__bf16)x0.x; v[1] = (__bf16)x0.y; v[2] = (__bf16)x0.z; v[3] = (__bf16)x0.w;
        v[4] = (__bf16)x1.x; v[5] = (__bf16)x1.y; v[6] = (__bf16)x1.z; v[7] = (__bf16)x1.w;
        *reinterpret_cast<bf16x8*>(&alds[c * 8]) = v;
    }
    __syncthreads();

    const int on    = lane & 15;
    const int kg0   = lane >> 4;
    const int o_row = o_base + wid * 16 + on;

    const float* __restrict__ mu_p = w_mu  + (size_t)o_row * IN_ + kg0 * 8;
    const float* __restrict__ et_p = w_eta + (size_t)o_row * IN_ + kg0 * 8;
    const float* __restrict__ ep_p = eps_w + ((size_t)b * OUT_ + o_row) * IN_ + kg0 * 8;
    const __bf16* __restrict__ a_p = alds + lane * 8;

    f32x4 acc = {0.0f, 0.0f, 0.0f, 0.0f};
    #pragma unroll
    for (int kt = 0; kt < 32; ++kt) {
        const int i_ = kt * 32;
        const float4 m0 = *reinterpret_cast<const float4*>(mu_p + i_);
        const float4 m1 = *reinterpret_cast<const float4*>(mu_p + i_ + 4);
        const float4 s0 = *reinterpret_cast<const float4*>(et_p + i_);
        const float4 s1 = *reinterpret_cast<const float4*>(et_p + i_ + 4);
        const float4 e0 = *reinterpret_cast<const float4*>(ep_p + i_);
        const float4 e1 = *reinterpret_cast<const float4*>(ep_p + i_ + 4);
        const float mm[8] = {m0.x, m0.y, m0.z, m0.w, m1.x, m1.y, m1.z, m1.w};
        const float ss[8] = {s0.x, s0.y, s0.z, s0.w, s1.x, s1.y, s1.z, s1.w};
        const float ee[8] = {e0.x, e0.y, e0.z, e0.w, e1.x, e1.y, e1.z, e1.w};
        bf16x8 bfrag;
        #pragma unroll
        for (int q = 0; q < 8; ++q) {
            const float sp_ = __logf(1.0f + __expf(ss[q])) + 1e-6f;
            bfrag[q] = (__bf16)__expf(fmaf(sp_, ee[q], mm[q]));
        }
        const bf16x8 afrag = *reinterpret_cast<const bf16x8*>(a_p + kt * 512);
        acc = __builtin_amdgcn_mfma_f32_16x16x32_bf16(afrag, bfrag, acc, 0, 0, 0);
    }

    const float bias = fmaf(softplus_f(b_eta[o_row]) + 1e-6f,
                            eps_b[(size_t)b * OUT_ + o_row], b_mu[o_row]);
    #pragma unroll
    for (int rr = 0; rr < 4; ++rr) {
        const int s = kg0 * 4 + rr;
        out[((size_t)s * B_ + b) * OUT_ + o_row] = acc[rr] + bias;
    }
}

extern "C" void kernel_launch(void* const* d_in, const int* in_sizes, int n_in,
                              void* d_out, int out_size, void* d_ws, size_t ws_size,
                              hipStream_t stream)
{
    const float* input = (const float*)d_in[0];
    const float* w_mu  = (const float*)d_in[1];
    const float* w_eta = (const float*)d_in[2];
    const float* b_mu  = (const float*)d_in[3];
    const float* b_eta = (const float*)d_in[4];
    const float* eps_w = (const float*)d_in[5];
    const float* eps_b = (const float*)d_in[6];

    float* out = (float*)d_out;
    float* kl  = out + (size_t)S_ * B_ * OUT_;   // offsets 524288, 524289

    // ws layout
    const size_t TBL_OFF = 0;                                  // 4 MB frag-ordered table
    const size_t A_OFF   = (size_t)4 * 1024 * 1024;            // 1 MB bf16 a-frags
    const size_t KLP_OFF = (size_t)5 * 1024 * 1024;            // 4 KB kl_w partials
    const size_t NEED    = KLP_OFF + 4096;

    if (ws_size >= NEED) {
        unsigned* tbl  = (unsigned*)((char*)d_ws + TBL_OFF);
        __bf16*   a_ws = (__bf16*)((char*)d_ws + A_OFF);
        float*    klp  = (float*)((char*)d_ws + KLP_OFF);

        bpl_pre2<<<1056, 256, 0, stream>>>(input, w_mu, w_eta, tbl, a_ws, klp);
        bpl_fused<<<2049, 512, 0, stream>>>(tbl, a_ws, eps_w, b_mu, b_eta, eps_b,
                                            klp, out, kl);
    } else {
        hipMemsetAsync(kl, 0, 2 * sizeof(float), stream);
        bpl_pre_fb<<<1024, 256, 0, stream>>>(w_mu, w_eta, b_mu, b_eta, kl);
        bpl_mfma_fb<<<512, 256, 0, stream>>>(input, w_mu, w_eta, b_mu, b_eta,
                                             eps_w, eps_b, out);
    }
}